// Round 8
// baseline (28928.207 us; speedup 1.0000x reference)
//
#include <hip/hip_runtime.h>
#include <hip/hip_cooperative_groups.h>

namespace cg = cooperative_groups;

// LSTM classifier, MI355X.
// emb = glove[ids];  x_t = [emb_t, emb_{t-1}]
// x @ W_ih^T == G1[ids_t] + G2[ids_{t-1}]  (G tables precomputed by tab_gemm)
// R7 post-mortem: VGPR pinned at 128 three rounds straight -> compiler
// serializes every load->use; step = ~81K cycles of summed latencies.
// R8: cooperative-grid redesign. 320 single-wave WGs = 16 row-groups x 20
// col-tiles. Each wave: B-frags (41KB) cached in LDS ONCE; per step only
// 10 A-loads (h via global hbuf) + 40 ds_read + 40 MFMA + reg epilogue +
// grid.sync(). No per-step W_hh traffic, no intra-WG barrier, gathers
// prefetched and drained inside the sync spin.
//
// ws layout (full path):
//   WhhS    @ 0          819,200 B  [80 tile(ct*4+gb)][10 ks][64 L][8] bf16
//   hbuf    @ 819,200    327,680 B  [2][16 rg][16 row][320] bf16   (full)
//   poolbuf @ 1,146,880  311,296 B  [16 rg][16 row][304] f32       (full)
//   (fallback WihS occupies 819,200..2,375,680 instead of hbuf/poolbuf)
//   biasq   @ 2,375,680    5,120 B  [320*4] f32 quad-interleaved
//   Wq      @ 2,380,800 1,536,000 B (full only)
//   G       @ 3,916,800 240,000,000B [2][50000][1200] bf16, col' = j*4+gate
// FULL total = 243,916,800 B; smaller ws -> on-the-fly fallback kernel.

typedef __attribute__((ext_vector_type(8))) short s16x8;
typedef __attribute__((ext_vector_type(4))) short s16x4;
typedef __attribute__((ext_vector_type(4))) float f32x4;

#define FULL_WS_BYTES 243916800ull

__device__ __forceinline__ float bf2f(short s) {
  unsigned u = ((unsigned)(unsigned short)s) << 16;
  float f; __builtin_memcpy(&f, &u, 4); return f;
}
__device__ __forceinline__ short f2bf(float f) {
  unsigned u; __builtin_memcpy(&u, &f, 4);
  unsigned r = u + 0x7fffu + ((u >> 16) & 1u);   // RNE
  return (short)(r >> 16);
}
__device__ __forceinline__ f32x4 mfma16(s16x8 a, s16x8 b, f32x4 c) {
  return __builtin_amdgcn_mfma_f32_16x16x32_bf16(a, b, c, 0, 0, 0);
}
__device__ __forceinline__ float sigm(float x) { return 1.f / (1.f + __expf(-x)); }
__device__ __forceinline__ float tanh_(float x) {
  float e = __expf(2.f * x);          // inf-safe
  return 1.f - 2.f / (e + 1.f);
}

// ---------------- prep: weight fragment swizzles + bias ----------------
__global__ void prep_w(const float* __restrict__ Wih, const float* __restrict__ Whh_in,
                       const float* __restrict__ bih, const float* __restrict__ bhh,
                       short* __restrict__ Wq, short* __restrict__ WhhS,
                       short* __restrict__ WihS, float* __restrict__ biasq, int full) {
  int idx = blockIdx.x * 256 + threadIdx.x;       // 960*256 = 245,760
  if (idx < 96000) {                              // Wq (full path only)
    if (!full) return;
    int tab = idx / 48000; int r = idx % 48000;
    int L = r % 64;
    int colp = (r / 640) * 16 + (L & 15);
    int rowW = (colp & 3) * 300 + (colp >> 2);    // gate*300 + j
#pragma unroll
    for (int i = 0; i < 8; ++i) {
      int k = ((r / 64) % 10) * 32 + (L >> 4) * 8 + i;
      float v = (k < 300) ? Wih[(size_t)rowW * 600 + 300 * tab + k] : 0.f;
      Wq[(size_t)idx * 8 + i] = f2bf(v);
    }
  } else if (idx < 147200) {                      // WhhS
    int r = idx - 96000;
    int tIdx = r / 640; int L = r % 64;
    int ct = tIdx >> 2, gb = tIdx & 3;
    int j = ct * 16 + (L & 15);
#pragma unroll
    for (int i = 0; i < 8; ++i) {
      int k = ((r / 64) % 10) * 32 + (L >> 4) * 8 + i;
      float v = (j < 300 && k < 300) ? Whh_in[(size_t)(gb * 300 + j) * 300 + k] : 0.f;
      WhhS[(size_t)r * 8 + i] = f2bf(v);
    }
  } else if (idx < 244480) {                      // WihS (fallback ONLY; full path
    if (full) return;                             // reuses this region as hbuf!)
    int r = idx - 147200;
    int tile = r / 1216; int L = r % 64;
    int ct = tile >> 2, gb = tile & 3;
    int j = ct * 16 + (L & 15);
    int ksg = (r / 64) % 19;
#pragma unroll
    for (int i = 0; i < 8; ++i) {
      int k = ksg * 32 + (L >> 4) * 8 + i;
      float v = (j < 300 && k < 600) ? Wih[(size_t)(gb * 300 + j) * 600 + k] : 0.f;
      WihS[(size_t)r * 8 + i] = f2bf(v);
    }
  } else if (idx < 245760) {                      // biasq
    int r = idx - 244480; int j = r >> 2, gb = r & 3;
    biasq[r] = (j < 300) ? (bih[gb * 300 + j] + bhh[gb * 300 + j]) : 0.f;
  }
}

// ---------------- table GEMM: G[tab][v][col'] = glove @ W^T ----------------
__device__ __forceinline__ s16x8 loadA_gl(const float* __restrict__ g, int r, int k0) {
  s16x8 v;
  if (r < 50000) {
    if (k0 + 8 <= 300) {
      const float* p = g + (size_t)r * 300 + k0;
      f32x4 a = *(const f32x4*)p, b = *(const f32x4*)(p + 4);
      v[0] = f2bf(a.x); v[1] = f2bf(a.y); v[2] = f2bf(a.z); v[3] = f2bf(a.w);
      v[4] = f2bf(b.x); v[5] = f2bf(b.y); v[6] = f2bf(b.z); v[7] = f2bf(b.w);
    } else {
#pragma unroll
      for (int i = 0; i < 8; ++i) {
        int k = k0 + i;
        v[i] = (k < 300) ? f2bf(g[(size_t)r * 300 + k]) : (short)0;
      }
    }
  } else {
#pragma unroll
    for (int i = 0; i < 8; ++i) v[i] = 0;
  }
  return v;
}

__global__ __launch_bounds__(256, 2) void tab_gemm(const float* __restrict__ gl,
                                                   const short* __restrict__ Wq,
                                                   short* __restrict__ G) {
  int bid = blockIdx.x;                 // 391*15 blocks
  int nt = bid % 15, mt = bid / 15;
  int tid = threadIdx.x, L = tid & 63, w = tid >> 6;
  int ln = L & 15, kg = L >> 4;
  int v0 = mt * 128;

  f32x4 acc[2][2][5];
#pragma unroll
  for (int a = 0; a < 2; ++a)
#pragma unroll
    for (int b = 0; b < 2; ++b)
#pragma unroll
      for (int c = 0; c < 5; ++c) acc[a][b][c] = (f32x4){0.f, 0.f, 0.f, 0.f};

#pragma unroll
  for (int ks = 0; ks < 10; ++ks) {
    int r0 = v0 + (2 * w) * 16 + ln;
    int k0 = ks * 32 + kg * 8;
    s16x8 A0 = loadA_gl(gl, r0, k0);
    s16x8 A1 = loadA_gl(gl, r0 + 16, k0);
#pragma unroll
    for (int tab = 0; tab < 2; ++tab)
#pragma unroll
      for (int ctl = 0; ctl < 5; ++ctl) {
        const short* bp = Wq + ((((size_t)tab * 75 + nt * 5 + ctl) * 10 + ks) * 64 + L) * 8;
        s16x8 B = *(const s16x8*)bp;
        acc[tab][0][ctl] = mfma16(A0, B, acc[tab][0][ctl]);
        acc[tab][1][ctl] = mfma16(A1, B, acc[tab][1][ctl]);
      }
  }
#pragma unroll
  for (int tab = 0; tab < 2; ++tab)
#pragma unroll
    for (int rtl = 0; rtl < 2; ++rtl)
#pragma unroll
      for (int ctl = 0; ctl < 5; ++ctl)
#pragma unroll
        for (int r = 0; r < 4; ++r) {
          int v = v0 + (2 * w + rtl) * 16 + kg * 4 + r;
          if (v < 50000) {
            int colp = nt * 80 + ctl * 16 + ln;
            G[((size_t)tab * 50000 + v) * 1200 + colp] = f2bf(acc[tab][rtl][ctl][r]);
          }
        }
}

// ---------------- cooperative recurrent kernel: 320 WGs x 64 thr ----------------
// WG (rg, ct): rg = row-group of 16 batch rows, ct = 16 gate-cols (j = ct*16+ln).
// B-fragments for this ct live in LDS (filled once). h exchanged via global hbuf.
__global__ __launch_bounds__(64, 1) void lstm_coop(
    const int* __restrict__ ids, const short* __restrict__ G,
    const short* __restrict__ Whh, const float* __restrict__ biasq,
    short* __restrict__ hbuf, float* __restrict__ poolbuf) {
  __shared__ short Blds[4][10][64][8];            // 40,960 B

  cg::grid_group grid = cg::this_grid();

  const int L = threadIdx.x;                      // one wave per WG
  const int ln = L & 15, kg = L >> 4;
  const int bid = blockIdx.x;
  const int rg = bid / 20, ct = bid % 20;
  const int b0 = rg * 16;
  const int j = ct * 16 + ln;                     // gate col (may be >= 300 pad)
  const int jcl = (j < 300) ? j : 299;
  const bool jok = (j < 300);

  // fill B LDS cache (once): same linear order as WhhS
  {
    const short* wsrc = Whh + (size_t)ct * 4 * 5120;
    short* bl = &Blds[0][0][0][0];
    for (int i = L; i < 2560; i += 64)
      *(s16x8*)(bl + i * 8) = *(const s16x8*)(wsrc + i * 8);
  }

  // zero our slice of hbuf (both buffers, incl. pad cols) -> h0 = 0
#pragma unroll
  for (int buf = 0; buf < 2; ++buf)
#pragma unroll
    for (int r = 0; r < 4; ++r)
      hbuf[((size_t)(buf * 16 + rg) * 16 + kg * 4 + r) * 320 + j] = 0;

  const f32x4 bq = *(const f32x4*)(biasq + 4 * j);
  float creg[4] = {}, pool[4] = {};

  // gather prefetch for step 0 (g2 = 0 at t=0)
  const s16x4 zq = (s16x4){0, 0, 0, 0};
  int id_cur[4];
  s16x4 gq1[4], gq2[4];
#pragma unroll
  for (int r = 0; r < 4; ++r) {
    id_cur[r] = ids[(size_t)(b0 + kg * 4 + r) * 512 + 0];
    gq2[r] = zq;
    gq1[r] = *(const s16x4*)(G + (size_t)id_cur[r] * 1200 + 4 * jcl);
  }

  __threadfence();
  grid.sync();                                    // hbuf zeros visible grid-wide

  for (int t = 0; t < 512; ++t) {
    // prefetch ids for t+1
    int idn[4];
    {
      int tn = (t < 511) ? t + 1 : 511;
#pragma unroll
      for (int r = 0; r < 4; ++r)
        idn[r] = ids[(size_t)(b0 + kg * 4 + r) * 512 + tn];
    }

    // A fragments: h_{t-1} from hbuf[(t+1)&1][rg]  (A row = L&15 = batch row)
    const short* hsrc = hbuf + (size_t)(((t + 1) & 1) * 16 + rg) * 16 * 320;
    s16x8 A[10];
#pragma unroll
    for (int ks = 0; ks < 10; ++ks)
      A[ks] = *(const s16x8*)(hsrc + (L & 15) * 320 + ks * 32 + kg * 8);

    // 40 MFMA, B from LDS (2-way bank alias = free)
    f32x4 acc[4];
#pragma unroll
    for (int gb = 0; gb < 4; ++gb) {
      f32x4 a = (f32x4){0.f, 0.f, 0.f, 0.f};
#pragma unroll
      for (int ks = 0; ks < 10; ++ks)
        a = mfma16(A[ks], *(const s16x8*)(&Blds[gb][ks][L][0]), a);
      acc[gb] = a;
    }

    // issue gathers for t+1 (drain happens inside grid.sync spin -> hidden)
    s16x4 gq1n[4], gq2n[4];
    if (t < 511) {
#pragma unroll
      for (int r = 0; r < 4; ++r) {
        gq1n[r] = (t < 510)
            ? *(const s16x4*)(G + (size_t)idn[r] * 1200 + 4 * jcl) : zq;
        gq2n[r] =
            *(const s16x4*)(G + ((size_t)50000 + id_cur[r]) * 1200 + 4 * jcl);
      }
    }

    // epilogue: register-resident gathers + bias + activations + c/h update
    short* hdst = hbuf + (size_t)((t & 1) * 16 + rg) * 16 * 320;
#pragma unroll
    for (int r = 0; r < 4; ++r) {
      s16x4 q1 = gq1[r], q2 = gq2[r];
      float pi = acc[0][r] + bf2f(q1.x) + bf2f(q2.x) + bq.x;
      float pf = acc[1][r] + bf2f(q1.y) + bf2f(q2.y) + bq.y;
      float pg = acc[2][r] + bf2f(q1.z) + bf2f(q2.z) + bq.z;
      float po = acc[3][r] + bf2f(q1.w) + bf2f(q2.w) + bq.w;
      float iv = sigm(pi), fv = sigm(pf), gv = tanh_(pg), ov = sigm(po);
      float c = fv * creg[r] + iv * gv;
      creg[r] = c;
      float h = ov * tanh_(c);
      if (jok) {
        pool[r] += h;
        hdst[(kg * 4 + r) * 320 + j] = f2bf(h);   // pad cols stay zero
      }
    }

#pragma unroll
    for (int r = 0; r < 4; ++r) id_cur[r] = idn[r];
    if (t < 511) {
#pragma unroll
      for (int r = 0; r < 4; ++r) { gq1[r] = gq1n[r]; gq2[r] = gq2n[r]; }
    }

    __threadfence();
    grid.sync();
  }

  if (jok) {
#pragma unroll
    for (int r = 0; r < 4; ++r)
      poolbuf[(size_t)(rg * 16 + kg * 4 + r) * 304 + j] = pool[r] * (1.f / 512.f);
  }
}

// ---------------- classifier tail: 16 WGs x 256 thr ----------------
__global__ __launch_bounds__(256) void tail_k(const float* __restrict__ poolbuf,
    const float* __restrict__ W1, const float* __restrict__ b1,
    const float* __restrict__ W2, const float* __restrict__ b2,
    float* __restrict__ out) {
  __shared__ float pool[16][304];
  __shared__ float l1[16][100];
  __shared__ float l2[16][5];
  const int tid = threadIdx.x, rg = blockIdx.x;

  for (int i = tid; i < 16 * 304; i += 256)
    (&pool[0][0])[i] = poolbuf[(size_t)rg * 16 * 304 + i];
  __syncthreads();

  for (int k = 0; k < 7; ++k) {                   // 1600 dots of 300
    int it = tid + 256 * k;
    if (it < 1600) {
      int b = it & 15, o = it >> 4;
      const float* w1r = W1 + (size_t)o * 300;
      float d = b1[o];
      for (int q = 0; q < 75; ++q) {
        f32x4 pv = *(const f32x4*)(&pool[b][q * 4]);
        f32x4 wv = *(const f32x4*)(w1r + q * 4);
        d += pv.x * wv.x + pv.y * wv.y + pv.z * wv.z + pv.w * wv.w;
      }
      l1[b][o] = sigm(d);
    }
  }
  __syncthreads();
  if (tid < 80) {
    int b = tid & 15, o = tid >> 4;
    float d = b2[o];
    for (int q = 0; q < 100; ++q) d += l1[b][q] * W2[o * 100 + q];
    l2[b][o] = sigm(d);
  }
  __syncthreads();
  if (tid < 16) {
    float x0 = l2[tid][0], x1 = l2[tid][1], x2 = l2[tid][2],
          x3 = l2[tid][3], x4 = l2[tid][4];
    float m = fmaxf(fmaxf(fmaxf(x0, x1), fmaxf(x2, x3)), x4);
    float ssum = __expf(x0 - m) + __expf(x1 - m) + __expf(x2 - m) +
                 __expf(x3 - m) + __expf(x4 - m);
    float ls = __logf(ssum);
    float* po = out + (size_t)(rg * 16 + tid) * 5;
    po[0] = x0 - m - ls; po[1] = x1 - m - ls; po[2] = x2 - m - ls;
    po[3] = x3 - m - ls; po[4] = x4 - m - ls;
  }
}

// ---------------- fallback (small ws): on-the-fly input GEMM, 16 WGs ----------------
struct TailShF { float pool[16][304]; float l1[16][100]; float l2[16][5]; };
struct LoopOF { short h[2][16][330]; short x[2][16][616]; };
union ShFb { LoopOF loop; TailShF tail; };

__global__ __launch_bounds__(512, 2) void lstm_fb(
    const int* __restrict__ ids, const float* __restrict__ glove,
    const short* __restrict__ Whh, const short* __restrict__ WihF,
    const float* __restrict__ biasq,
    const float* __restrict__ W1, const float* __restrict__ b1,
    const float* __restrict__ W2, const float* __restrict__ b2,
    float* __restrict__ out) {
  __shared__ ShFb sh;

  const int tid = threadIdx.x;
  const int L = tid & 63, w = tid >> 6;
  const int ln = L & 15, kg = L >> 4;
  const int b0 = blockIdx.x * 16;
  const int nct = (w < 4) ? 3 : 2;
  const int cts[3] = {w, w + 8, w + 16};

  int jj[3];
  f32x4 bq[3];
#pragma unroll
  for (int s = 0; s < 3; ++s) {
    jj[s] = cts[s] * 16 + ln;
    if (s < nct) bq[s] = *(const f32x4*)(biasq + 4 * jj[s]);
  }
  float creg[3][4] = {}, pool[3][4] = {};

  for (int i = tid; i < (int)(sizeof(sh.loop) / 2); i += 512) ((short*)&sh.loop)[i] = 0;
  __syncthreads();

  for (int t = 0; t < 512; ++t) {
    {
      int r2 = tid >> 5, cl = tid & 31;
      int idt = (t < 511) ? ids[(size_t)(b0 + r2) * 512 + t] : 0;
#pragma unroll
      for (int q = 0; q < 10; ++q) {
        int c = cl + 32 * q;
        if (c < 300) {
          float v = (t < 511) ? glove[(size_t)idt * 300 + c] : 0.f;
          short bv = f2bf(v);
          sh.loop.x[t & 1][r2][c] = bv;
          sh.loop.x[(t + 1) & 1][r2][300 + c] = bv;
        }
      }
      __syncthreads();
    }

    s16x8 A[10];
#pragma unroll
    for (int ks = 0; ks < 10; ++ks)
      A[ks] = *(const s16x8*)(&sh.loop.h[(t + 1) & 1][ln][ks * 32 + kg * 8]);
    s16x8 AX[19];
#pragma unroll
    for (int ks = 0; ks < 19; ++ks)
      AX[ks] = *(const s16x8*)(&sh.loop.x[t & 1][ln][ks * 32 + kg * 8]);

    f32x4 acc[3][4];
#pragma unroll
    for (int s = 0; s < 3; ++s) {
      if (s >= nct) continue;
#pragma unroll
      for (int gb = 0; gb < 4; ++gb) {
        f32x4 a = (f32x4){0.f, 0.f, 0.f, 0.f};
        const short* wb = Whh + (size_t)(cts[s] * 4 + gb) * 5120;
#pragma unroll
        for (int ks = 0; ks < 10; ++ks)
          a = mfma16(A[ks], *(const s16x8*)(wb + (ks * 64 + L) * 8), a);
        const short* wx = WihF + (size_t)(cts[s] * 4 + gb) * 19 * 512;
#pragma unroll
        for (int ks = 0; ks < 19; ++ks)
          a = mfma16(AX[ks], *(const s16x8*)(wx + (ks * 64 + L) * 8), a);
        acc[s][gb] = a;
      }
    }

#pragma unroll
    for (int s = 0; s < 3; ++s) {
      if (s >= nct) continue;
      const int j = jj[s];
#pragma unroll
      for (int r = 0; r < 4; ++r) {
        float pi = acc[s][0][r] + bq[s].x;
        float pf = acc[s][1][r] + bq[s].y;
        float pg = acc[s][2][r] + bq[s].z;
        float po = acc[s][3][r] + bq[s].w;
        float iv = sigm(pi), fv = sigm(pf), gv = tanh_(pg), ov = sigm(po);
        float c = fv * creg[s][r] + iv * gv;
        creg[s][r] = c;
        float h = ov * tanh_(c);
        if (j >= 300) h = 0.f;
        pool[s][r] += h;
        sh.loop.h[t & 1][kg * 4 + r][j] = f2bf(h);
      }
    }
    __syncthreads();
  }

#pragma unroll
  for (int s = 0; s < 3; ++s) {
    if (s >= nct) continue;
    if (jj[s] < 300) {
#pragma unroll
      for (int r = 0; r < 4; ++r)
        sh.tail.pool[kg * 4 + r][jj[s]] = pool[s][r] * (1.f / 512.f);
    }
  }
  __syncthreads();
  for (int k = 0; k < 4; ++k) {
    int it = tid + 512 * k;
    if (it < 1600) {
      int b = it & 15, o = it >> 4;
      const float* w1r = W1 + (size_t)o * 300;
      float d = b1[o];
      for (int q = 0; q < 75; ++q) {
        f32x4 pv = *(const f32x4*)(&sh.tail.pool[b][q * 4]);
        f32x4 wv = *(const f32x4*)(w1r + q * 4);
        d += pv.x * wv.x + pv.y * wv.y + pv.z * wv.z + pv.w * wv.w;
      }
      sh.tail.l1[b][o] = sigm(d);
    }
  }
  __syncthreads();
  if (tid < 80) {
    int b = tid & 15, o = tid >> 4;
    float d = b2[o];
    for (int q = 0; q < 100; ++q) d += sh.tail.l1[b][q] * W2[o * 100 + q];
    sh.tail.l2[b][o] = sigm(d);
  }
  __syncthreads();
  if (tid < 16) {
    float x0 = sh.tail.l2[tid][0], x1 = sh.tail.l2[tid][1], x2 = sh.tail.l2[tid][2],
          x3 = sh.tail.l2[tid][3], x4 = sh.tail.l2[tid][4];
    float m = fmaxf(fmaxf(fmaxf(x0, x1), fmaxf(x2, x3)), x4);
    float ssum = __expf(x0 - m) + __expf(x1 - m) + __expf(x2 - m) +
                 __expf(x3 - m) + __expf(x4 - m);
    float ls = __logf(ssum);
    float* po = out + (size_t)(b0 + tid) * 5;
    po[0] = x0 - m - ls; po[1] = x1 - m - ls; po[2] = x2 - m - ls;
    po[3] = x3 - m - ls; po[4] = x4 - m - ls;
  }
}

extern "C" void kernel_launch(void* const* d_in, const int* in_sizes, int n_in,
                              void* d_out, int out_size, void* d_ws, size_t ws_size,
                              hipStream_t stream) {
  const int*   ids   = (const int*)d_in[0];
  const float* glove = (const float*)d_in[2];
  const float* W_ih  = (const float*)d_in[3];
  const float* W_hh  = (const float*)d_in[4];
  const float* b_ih  = (const float*)d_in[5];
  const float* b_hh  = (const float*)d_in[6];
  const float* W1    = (const float*)d_in[7];
  const float* b1    = (const float*)d_in[8];
  const float* W2    = (const float*)d_in[9];
  const float* b2    = (const float*)d_in[10];
  float* out = (float*)d_out;

  char* ws = (char*)d_ws;
  short* WhhS    = (short*)(ws);                 //   819,200 B
  short* WihS    = (short*)(ws + 819200);        // fallback only (1,556,480 B)
  short* hbuf    = (short*)(ws + 819200);        // full only (327,680 B)
  float* poolbuf = (float*)(ws + 1146880);       // full only (311,296 B)
  float* biasq   = (float*)(ws + 2375680);       //     5,120 B
  short* Wq      = (short*)(ws + 2380800);       // 1,536,000 B (full only)
  short* G       = (short*)(ws + 3916800);       // 240,000,000 B (full only)

  const int full = (ws_size >= (size_t)FULL_WS_BYTES) ? 1 : 0;

  prep_w<<<960, 256, 0, stream>>>(W_ih, W_hh, b_ih, b_hh, Wq, WhhS, WihS, biasq, full);
  if (full) {
    tab_gemm<<<5865, 256, 0, stream>>>(glove, Wq, G);
    void* args[] = {(void*)&ids, (void*)&G, (void*)&WhhS, (void*)&biasq,
                    (void*)&hbuf, (void*)&poolbuf};
    hipLaunchCooperativeKernel((const void*)lstm_coop, dim3(320), dim3(64),
                               args, 0, stream);
    tail_k<<<16, 256, 0, stream>>>(poolbuf, W1, b1, W2, b2, out);
  } else {
    lstm_fb<<<16, 512, 0, stream>>>(ids, glove, WhhS, WihS, biasq,
                                    W1, b1, W2, b2, out);
  }
}

// Round 9
// 13286.581 us; speedup vs baseline: 2.1772x; 2.1772x over previous
//
#include <hip/hip_runtime.h>

// LSTM classifier, MI355X.
// emb = glove[ids];  x_t = [emb_t, emb_{t-1}]
// x @ W_ih^T == G1[ids_t] + G2[ids_{t-1}]  (G tables precomputed by tab_gemm)
// R8 post-mortem: grid.sync = 56us/step -> cooperative structure dead.
// R9: back to 16 WGs (one per 16 batch rows, intra-WG barrier), but W_hh is
// REGISTER-PERSISTENT: 10 waves/WG, wave w owns col-tiles {w, w+10} = 8 B-tiles
// = 320 VGPRs loaded once (unified VGPR/AGPR file 2MB/CU; 819KB W_hh fits).
// Per step: 20 VM loads issued first (latency hides under MFMA), 10 LDS A-loads,
// 80 MFMA from registers, reg epilogue, h-store, one barrier (vmcnt empty).
//
// ws layout:
//   WhhS  @ 0          819,200 B   [80 tile(ct*4+gb)][10 ks][64 L][8] bf16
//   WihS  @ 819,200  1,556,480 B   (fallback only)
//   biasq @ 2,375,680    5,120 B   [320*4] f32 quad-interleaved
//   Wq    @ 2,380,800 1,536,000 B  (full only)
//   G     @ 3,916,800 240,000,000B [2][50000][1200] bf16, col' = j*4+gate
// FULL total = 243,916,800 B; smaller ws -> on-the-fly fallback kernel.

typedef __attribute__((ext_vector_type(8))) short s16x8;
typedef __attribute__((ext_vector_type(4))) short s16x4;
typedef __attribute__((ext_vector_type(4))) float f32x4;

#define FULL_WS_BYTES 243916800ull

__device__ __forceinline__ float bf2f(short s) {
  unsigned u = ((unsigned)(unsigned short)s) << 16;
  float f; __builtin_memcpy(&f, &u, 4); return f;
}
__device__ __forceinline__ short f2bf(float f) {
  unsigned u; __builtin_memcpy(&u, &f, 4);
  unsigned r = u + 0x7fffu + ((u >> 16) & 1u);   // RNE
  return (short)(r >> 16);
}
__device__ __forceinline__ f32x4 mfma16(s16x8 a, s16x8 b, f32x4 c) {
  return __builtin_amdgcn_mfma_f32_16x16x32_bf16(a, b, c, 0, 0, 0);
}
__device__ __forceinline__ float sigm(float x) { return 1.f / (1.f + __expf(-x)); }
__device__ __forceinline__ float tanh_(float x) {
  float e = __expf(2.f * x);          // inf-safe
  return 1.f - 2.f / (e + 1.f);
}

// ---------------- prep: weight fragment swizzles + bias ----------------
__global__ void prep_w(const float* __restrict__ Wih, const float* __restrict__ Whh_in,
                       const float* __restrict__ bih, const float* __restrict__ bhh,
                       short* __restrict__ Wq, short* __restrict__ WhhS,
                       short* __restrict__ WihS, float* __restrict__ biasq, int full) {
  int idx = blockIdx.x * 256 + threadIdx.x;       // 960*256 = 245,760
  if (idx < 96000) {                              // Wq (full path only)
    if (!full) return;
    int tab = idx / 48000; int r = idx % 48000;
    int L = r % 64;
    int colp = (r / 640) * 16 + (L & 15);
    int rowW = (colp & 3) * 300 + (colp >> 2);    // gate*300 + j
#pragma unroll
    for (int i = 0; i < 8; ++i) {
      int k = ((r / 64) % 10) * 32 + (L >> 4) * 8 + i;
      float v = (k < 300) ? Wih[(size_t)rowW * 600 + 300 * tab + k] : 0.f;
      Wq[(size_t)idx * 8 + i] = f2bf(v);
    }
  } else if (idx < 147200) {                      // WhhS
    int r = idx - 96000;
    int tIdx = r / 640; int L = r % 64;
    int ct = tIdx >> 2, gb = tIdx & 3;
    int j = ct * 16 + (L & 15);
#pragma unroll
    for (int i = 0; i < 8; ++i) {
      int k = ((r / 64) % 10) * 32 + (L >> 4) * 8 + i;
      float v = (j < 300 && k < 300) ? Whh_in[(size_t)(gb * 300 + j) * 300 + k] : 0.f;
      WhhS[(size_t)r * 8 + i] = f2bf(v);
    }
  } else if (idx < 244480) {                      // WihS (fallback)
    int r = idx - 147200;
    int tile = r / 1216; int L = r % 64;
    int ct = tile >> 2, gb = tile & 3;
    int j = ct * 16 + (L & 15);
    int ksg = (r / 64) % 19;
#pragma unroll
    for (int i = 0; i < 8; ++i) {
      int k = ksg * 32 + (L >> 4) * 8 + i;
      float v = (j < 300 && k < 600) ? Wih[(size_t)(gb * 300 + j) * 600 + k] : 0.f;
      WihS[(size_t)r * 8 + i] = f2bf(v);
    }
  } else if (idx < 245760) {                      // biasq
    int r = idx - 244480; int j = r >> 2, gb = r & 3;
    biasq[r] = (j < 300) ? (bih[gb * 300 + j] + bhh[gb * 300 + j]) : 0.f;
  }
}

// ---------------- table GEMM: G[tab][v][col'] = glove @ W^T ----------------
__device__ __forceinline__ s16x8 loadA_gl(const float* __restrict__ g, int r, int k0) {
  s16x8 v;
  if (r < 50000) {
    if (k0 + 8 <= 300) {
      const float* p = g + (size_t)r * 300 + k0;
      f32x4 a = *(const f32x4*)p, b = *(const f32x4*)(p + 4);
      v[0] = f2bf(a.x); v[1] = f2bf(a.y); v[2] = f2bf(a.z); v[3] = f2bf(a.w);
      v[4] = f2bf(b.x); v[5] = f2bf(b.y); v[6] = f2bf(b.z); v[7] = f2bf(b.w);
    } else {
#pragma unroll
      for (int i = 0; i < 8; ++i) {
        int k = k0 + i;
        v[i] = (k < 300) ? f2bf(g[(size_t)r * 300 + k]) : (short)0;
      }
    }
  } else {
#pragma unroll
    for (int i = 0; i < 8; ++i) v[i] = 0;
  }
  return v;
}

__global__ __launch_bounds__(256, 2) void tab_gemm(const float* __restrict__ gl,
                                                   const short* __restrict__ Wq,
                                                   short* __restrict__ G) {
  int bid = blockIdx.x;                 // 391*15 blocks
  int nt = bid % 15, mt = bid / 15;
  int tid = threadIdx.x, L = tid & 63, w = tid >> 6;
  int ln = L & 15, kg = L >> 4;
  int v0 = mt * 128;

  f32x4 acc[2][2][5];
#pragma unroll
  for (int a = 0; a < 2; ++a)
#pragma unroll
    for (int b = 0; b < 2; ++b)
#pragma unroll
      for (int c = 0; c < 5; ++c) acc[a][b][c] = (f32x4){0.f, 0.f, 0.f, 0.f};

#pragma unroll
  for (int ks = 0; ks < 10; ++ks) {
    int r0 = v0 + (2 * w) * 16 + ln;
    int k0 = ks * 32 + kg * 8;
    s16x8 A0 = loadA_gl(gl, r0, k0);
    s16x8 A1 = loadA_gl(gl, r0 + 16, k0);
#pragma unroll
    for (int tab = 0; tab < 2; ++tab)
#pragma unroll
      for (int ctl = 0; ctl < 5; ++ctl) {
        const short* bp = Wq + ((((size_t)tab * 75 + nt * 5 + ctl) * 10 + ks) * 64 + L) * 8;
        s16x8 B = *(const s16x8*)bp;
        acc[tab][0][ctl] = mfma16(A0, B, acc[tab][0][ctl]);
        acc[tab][1][ctl] = mfma16(A1, B, acc[tab][1][ctl]);
      }
  }
#pragma unroll
  for (int tab = 0; tab < 2; ++tab)
#pragma unroll
    for (int rtl = 0; rtl < 2; ++rtl)
#pragma unroll
      for (int ctl = 0; ctl < 5; ++ctl)
#pragma unroll
        for (int r = 0; r < 4; ++r) {
          int v = v0 + (2 * w + rtl) * 16 + kg * 4 + r;
          if (v < 50000) {
            int colp = nt * 80 + ctl * 16 + ln;
            G[((size_t)tab * 50000 + v) * 1200 + colp] = f2bf(acc[tab][rtl][ctl][r]);
          }
        }
}

// ------- recurrent kernel, W_hh register-persistent: 16 WGs x 640 thr (10 waves) -------
struct TailSh10 { float pool[16][304]; float l1[16][100]; float l2[16][5]; };
struct LoopSh10 { short h[2][16][330]; };         // 21,120 B (stride 330: bank-stride 5)
union Sh10 { LoopSh10 loop; TailSh10 tail; };     // 26,176 B

__global__ __launch_bounds__(640, 1) void lstm_reg(
    const int* __restrict__ ids, const short* __restrict__ G,
    const short* __restrict__ Whh, const float* __restrict__ biasq,
    const float* __restrict__ W1, const float* __restrict__ b1,
    const float* __restrict__ W2, const float* __restrict__ b2,
    float* __restrict__ out) {
  __shared__ Sh10 sh;

  const int tid = threadIdx.x;
  const int L = tid & 63, w = tid >> 6;           // 10 waves
  const int ln = L & 15, kg = L >> 4;
  const int b0 = blockIdx.x * 16;
  const int ct0 = w, ct1 = w + 10;                // 20 col-tiles, 2 per wave

  const int j0 = ct0 * 16 + ln, j1 = ct1 * 16 + ln;
  const int jc0 = (j0 < 300) ? j0 : 299, jc1 = (j1 < 300) ? j1 : 299;
  const bool ok0 = (j0 < 300), ok1 = (j1 < 300);
  const f32x4 bq0 = *(const f32x4*)(biasq + 4 * j0);
  const f32x4 bq1 = *(const f32x4*)(biasq + 4 * j1);

  // ---- load W_hh B-fragments into persistent registers (once) ----
  s16x8 B0[4][10], B1[4][10];
#pragma unroll
  for (int gb = 0; gb < 4; ++gb)
#pragma unroll
    for (int ks = 0; ks < 10; ++ks) {
      B0[gb][ks] = *(const s16x8*)(Whh + (size_t)(ct0 * 4 + gb) * 5120 + (ks * 64 + L) * 8);
      B1[gb][ks] = *(const s16x8*)(Whh + (size_t)(ct1 * 4 + gb) * 5120 + (ks * 64 + L) * 8);
    }

  float creg[2][4] = {}, pool[2][4] = {};
  int id_cur[4], id_prev[4];
#pragma unroll
  for (int r = 0; r < 4; ++r) {
    id_cur[r] = ids[(size_t)(b0 + kg * 4 + r) * 512 + 0];
    id_prev[r] = id_cur[r];                       // unused at t=0 (g2=0)
  }

  for (int i = tid; i < (int)(sizeof(LoopSh10) / 2); i += 640) ((short*)&sh.loop)[i] = 0;
  __syncthreads();

  const s16x4 zq = (s16x4){0, 0, 0, 0};

  for (int t = 0; t < 512; ++t) {
    // phase 1: issue ALL VM loads first; latency hides under the MFMA phase
    // (MFMA depends only on LDS-A + register-B, never waits on these).
    s16x4 gq1[2][4], gq2[2][4];
#pragma unroll
    for (int r = 0; r < 4; ++r) {
      gq1[0][r] = (t != 511) ? *(const s16x4*)(G + (size_t)id_cur[r] * 1200 + 4 * jc0) : zq;
      gq1[1][r] = (t != 511) ? *(const s16x4*)(G + (size_t)id_cur[r] * 1200 + 4 * jc1) : zq;
      gq2[0][r] = (t != 0) ? *(const s16x4*)(G + ((size_t)50000 + id_prev[r]) * 1200 + 4 * jc0) : zq;
      gq2[1][r] = (t != 0) ? *(const s16x4*)(G + ((size_t)50000 + id_prev[r]) * 1200 + 4 * jc1) : zq;
    }
    int idn[4];
    {
      int tn = (t < 511) ? t + 1 : 511;
#pragma unroll
      for (int r = 0; r < 4; ++r)
        idn[r] = ids[(size_t)(b0 + kg * 4 + r) * 512 + tn];
    }

    // phase 2: A fragments from LDS h dbuf (read (t+1)&1)
    s16x8 A[10];
#pragma unroll
    for (int ks = 0; ks < 10; ++ks)
      A[ks] = *(const s16x8*)(&sh.loop.h[(t + 1) & 1][ln][ks * 32 + kg * 8]);

    // phase 3: 80 MFMA, B from registers
    f32x4 acc[2][4];
#pragma unroll
    for (int gb = 0; gb < 4; ++gb) {
      f32x4 a0 = (f32x4){0.f, 0.f, 0.f, 0.f};
      f32x4 a1 = (f32x4){0.f, 0.f, 0.f, 0.f};
#pragma unroll
      for (int ks = 0; ks < 10; ++ks) {
        a0 = mfma16(A[ks], B0[gb][ks], a0);
        a1 = mfma16(A[ks], B1[gb][ks], a1);
      }
      acc[0][gb] = a0; acc[1][gb] = a1;
    }

    // phase 4: epilogue (gathers have landed under the MFMA shadow)
#pragma unroll
    for (int s = 0; s < 2; ++s) {
      const int j = s ? j1 : j0;
      const bool ok = s ? ok1 : ok0;
      const f32x4 bq = s ? bq1 : bq0;
#pragma unroll
      for (int r = 0; r < 4; ++r) {
        s16x4 q1 = gq1[s][r], q2 = gq2[s][r];
        float pi = acc[s][0][r] + bf2f(q1.x) + bf2f(q2.x) + bq.x;
        float pf = acc[s][1][r] + bf2f(q1.y) + bf2f(q2.y) + bq.y;
        float pg = acc[s][2][r] + bf2f(q1.z) + bf2f(q2.z) + bq.z;
        float po = acc[s][3][r] + bf2f(q1.w) + bf2f(q2.w) + bq.w;
        float iv = sigm(pi), fv = sigm(pf), gv = tanh_(pg), ov = sigm(po);
        float c = fv * creg[s][r] + iv * gv;
        creg[s][r] = c;
        float h = ov * tanh_(c);
        if (ok) {                                 // pad cols stay zero in LDS
          pool[s][r] += h;
          sh.loop.h[t & 1][kg * 4 + r][j] = f2bf(h);
        }
      }
    }

#pragma unroll
    for (int r = 0; r < 4; ++r) { id_prev[r] = id_cur[r]; id_cur[r] = idn[r]; }
    __syncthreads();                              // vmcnt already drained -> cheap
  }

  // ---- tail: pooled mean -> l1 -> l2 -> log_softmax ----
#pragma unroll
  for (int s = 0; s < 2; ++s) {
    const int j = s ? j1 : j0;
    if (j < 300) {
#pragma unroll
      for (int r = 0; r < 4; ++r)
        sh.tail.pool[kg * 4 + r][j] = pool[s][r] * (1.f / 512.f);
    }
  }
  __syncthreads();

  for (int k = 0; k < 3; ++k) {                   // 1600 dots of 300
    int it = tid + 640 * k;
    if (it < 1600) {
      int b = it & 15, o = it >> 4;
      const float* w1r = W1 + (size_t)o * 300;
      float d = b1[o];
      for (int q = 0; q < 75; ++q) {
        f32x4 pv = *(const f32x4*)(&sh.tail.pool[b][q * 4]);
        f32x4 wv = *(const f32x4*)(w1r + q * 4);
        d += pv.x * wv.x + pv.y * wv.y + pv.z * wv.z + pv.w * wv.w;
      }
      sh.tail.l1[b][o] = sigm(d);
    }
  }
  __syncthreads();
  if (tid < 80) {
    int b = tid & 15, o = tid >> 4;
    float d = b2[o];
    for (int q = 0; q < 100; ++q) d += sh.tail.l1[b][q] * W2[o * 100 + q];
    sh.tail.l2[b][o] = sigm(d);
  }
  __syncthreads();
  if (tid < 16) {
    float x0 = sh.tail.l2[tid][0], x1 = sh.tail.l2[tid][1], x2 = sh.tail.l2[tid][2],
          x3 = sh.tail.l2[tid][3], x4 = sh.tail.l2[tid][4];
    float m = fmaxf(fmaxf(fmaxf(x0, x1), fmaxf(x2, x3)), x4);
    float ssum = __expf(x0 - m) + __expf(x1 - m) + __expf(x2 - m) +
                 __expf(x3 - m) + __expf(x4 - m);
    float ls = __logf(ssum);
    float* po = out + (size_t)(b0 + tid) * 5;
    po[0] = x0 - m - ls; po[1] = x1 - m - ls; po[2] = x2 - m - ls;
    po[3] = x3 - m - ls; po[4] = x4 - m - ls;
  }
}

// ---------------- fallback (small ws): on-the-fly input GEMM, 16 WGs ----------------
struct TailShF { float pool[16][304]; float l1[16][100]; float l2[16][5]; };
struct LoopOF { short h[2][16][330]; short x[2][16][616]; };
union ShFb { LoopOF loop; TailShF tail; };

__global__ __launch_bounds__(512, 2) void lstm_fb(
    const int* __restrict__ ids, const float* __restrict__ glove,
    const short* __restrict__ Whh, const short* __restrict__ WihF,
    const float* __restrict__ biasq,
    const float* __restrict__ W1, const float* __restrict__ b1,
    const float* __restrict__ W2, const float* __restrict__ b2,
    float* __restrict__ out) {
  __shared__ ShFb sh;

  const int tid = threadIdx.x;
  const int L = tid & 63, w = tid >> 6;
  const int ln = L & 15, kg = L >> 4;
  const int b0 = blockIdx.x * 16;
  const int nct = (w < 4) ? 3 : 2;
  const int cts[3] = {w, w + 8, w + 16};

  int jj[3];
  f32x4 bq[3];
#pragma unroll
  for (int s = 0; s < 3; ++s) {
    jj[s] = cts[s] * 16 + ln;
    if (s < nct) bq[s] = *(const f32x4*)(biasq + 4 * jj[s]);
  }
  float creg[3][4] = {}, pool[3][4] = {};

  for (int i = tid; i < (int)(sizeof(sh.loop) / 2); i += 512) ((short*)&sh.loop)[i] = 0;
  __syncthreads();

  for (int t = 0; t < 512; ++t) {
    {
      int r2 = tid >> 5, cl = tid & 31;
      int idt = (t < 511) ? ids[(size_t)(b0 + r2) * 512 + t] : 0;
#pragma unroll
      for (int q = 0; q < 10; ++q) {
        int c = cl + 32 * q;
        if (c < 300) {
          float v = (t < 511) ? glove[(size_t)idt * 300 + c] : 0.f;
          short bv = f2bf(v);
          sh.loop.x[t & 1][r2][c] = bv;
          sh.loop.x[(t + 1) & 1][r2][300 + c] = bv;
        }
      }
      __syncthreads();
    }

    s16x8 A[10];
#pragma unroll
    for (int ks = 0; ks < 10; ++ks)
      A[ks] = *(const s16x8*)(&sh.loop.h[(t + 1) & 1][ln][ks * 32 + kg * 8]);
    s16x8 AX[19];
#pragma unroll
    for (int ks = 0; ks < 19; ++ks)
      AX[ks] = *(const s16x8*)(&sh.loop.x[t & 1][ln][ks * 32 + kg * 8]);

    f32x4 acc[3][4];
#pragma unroll
    for (int s = 0; s < 3; ++s) {
      if (s >= nct) continue;
#pragma unroll
      for (int gb = 0; gb < 4; ++gb) {
        f32x4 a = (f32x4){0.f, 0.f, 0.f, 0.f};
        const short* wb = Whh + (size_t)(cts[s] * 4 + gb) * 5120;
#pragma unroll
        for (int ks = 0; ks < 10; ++ks)
          a = mfma16(A[ks], *(const s16x8*)(wb + (ks * 64 + L) * 8), a);
        const short* wx = WihF + (size_t)(cts[s] * 4 + gb) * 19 * 512;
#pragma unroll
        for (int ks = 0; ks < 19; ++ks)
          a = mfma16(AX[ks], *(const s16x8*)(wx + (ks * 64 + L) * 8), a);
        acc[s][gb] = a;
      }
    }

#pragma unroll
    for (int s = 0; s < 3; ++s) {
      if (s >= nct) continue;
      const int j = jj[s];
#pragma unroll
      for (int r = 0; r < 4; ++r) {
        float pi = acc[s][0][r] + bq[s].x;
        float pf = acc[s][1][r] + bq[s].y;
        float pg = acc[s][2][r] + bq[s].z;
        float po = acc[s][3][r] + bq[s].w;
        float iv = sigm(pi), fv = sigm(pf), gv = tanh_(pg), ov = sigm(po);
        float c = fv * creg[s][r] + iv * gv;
        creg[s][r] = c;
        float h = ov * tanh_(c);
        if (j >= 300) h = 0.f;
        pool[s][r] += h;
        sh.loop.h[t & 1][kg * 4 + r][j] = f2bf(h);
      }
    }
    __syncthreads();
  }

#pragma unroll
  for (int s = 0; s < 3; ++s) {
    if (s >= nct) continue;
    if (jj[s] < 300) {
#pragma unroll
      for (int r = 0; r < 4; ++r)
        sh.tail.pool[kg * 4 + r][jj[s]] = pool[s][r] * (1.f / 512.f);
    }
  }
  __syncthreads();
  for (int k = 0; k < 4; ++k) {
    int it = tid + 512 * k;
    if (it < 1600) {
      int b = it & 15, o = it >> 4;
      const float* w1r = W1 + (size_t)o * 300;
      float d = b1[o];
      for (int q = 0; q < 75; ++q) {
        f32x4 pv = *(const f32x4*)(&sh.tail.pool[b][q * 4]);
        f32x4 wv = *(const f32x4*)(w1r + q * 4);
        d += pv.x * wv.x + pv.y * wv.y + pv.z * wv.z + pv.w * wv.w;
      }
      sh.tail.l1[b][o] = sigm(d);
    }
  }
  __syncthreads();
  if (tid < 80) {
    int b = tid & 15, o = tid >> 4;
    float d = b2[o];
    for (int q = 0; q < 100; ++q) d += sh.tail.l1[b][q] * W2[o * 100 + q];
    sh.tail.l2[b][o] = sigm(d);
  }
  __syncthreads();
  if (tid < 16) {
    float x0 = sh.tail.l2[tid][0], x1 = sh.tail.l2[tid][1], x2 = sh.tail.l2[tid][2],
          x3 = sh.tail.l2[tid][3], x4 = sh.tail.l2[tid][4];
    float m = fmaxf(fmaxf(fmaxf(x0, x1), fmaxf(x2, x3)), x4);
    float ssum = __expf(x0 - m) + __expf(x1 - m) + __expf(x2 - m) +
                 __expf(x3 - m) + __expf(x4 - m);
    float ls = __logf(ssum);
    float* po = out + (size_t)(b0 + tid) * 5;
    po[0] = x0 - m - ls; po[1] = x1 - m - ls; po[2] = x2 - m - ls;
    po[3] = x3 - m - ls; po[4] = x4 - m - ls;
  }
}

extern "C" void kernel_launch(void* const* d_in, const int* in_sizes, int n_in,
                              void* d_out, int out_size, void* d_ws, size_t ws_size,
                              hipStream_t stream) {
  const int*   ids   = (const int*)d_in[0];
  const float* glove = (const float*)d_in[2];
  const float* W_ih  = (const float*)d_in[3];
  const float* W_hh  = (const float*)d_in[4];
  const float* b_ih  = (const float*)d_in[5];
  const float* b_hh  = (const float*)d_in[6];
  const float* W1    = (const float*)d_in[7];
  const float* b1    = (const float*)d_in[8];
  const float* W2    = (const float*)d_in[9];
  const float* b2    = (const float*)d_in[10];
  float* out = (float*)d_out;

  char* ws = (char*)d_ws;
  short* WhhS  = (short*)(ws);                   //   819,200 B
  short* WihS  = (short*)(ws + 819200);          // 1,556,480 B (fallback only)
  float* biasq = (float*)(ws + 2375680);         //     5,120 B
  short* Wq    = (short*)(ws + 2380800);         // 1,536,000 B (full only)
  short* G     = (short*)(ws + 3916800);         // 240,000,000 B (full only)

  const int full = (ws_size >= (size_t)FULL_WS_BYTES) ? 1 : 0;

  prep_w<<<960, 256, 0, stream>>>(W_ih, W_hh, b_ih, b_hh, Wq, WhhS, WihS, biasq, full);
  if (full) {
    tab_gemm<<<5865, 256, 0, stream>>>(glove, Wq, G);
    lstm_reg<<<16, 640, 0, stream>>>(ids, G, WhhS, biasq, W1, b1, W2, b2, out);
  } else {
    lstm_fb<<<16, 512, 0, stream>>>(ids, glove, WhhS, WihS, biasq,
                                    W1, b1, W2, b2, out);
  }
}

// Round 10
// 13089.969 us; speedup vs baseline: 2.2100x; 1.0150x over previous
//
#include <hip/hip_runtime.h>

// LSTM classifier, MI355X.
// emb = glove[ids];  x_t = [emb_t, emb_{t-1}]
// x @ W_ih^T == G1[ids_t] + G2[ids_{t-1}]  (G tables precomputed by tab_gemm)
// R9 post-mortem: VGPR_Count=84 proves the compiler re-materialized the
// "register-persistent" W_hh loads inside the t-loop -> still 800KB/step of
// serialized L2 latency. R10: pin all 80 B-fragments (320 VGPRs) with opaque
// inline asm ("+v" redefinition) so re-materialization is impossible. Per step:
// gathers issued first (overlap MFMA), 10 LDS A-reads, 80 all-register MFMA,
// reg epilogue, one barrier.
//
// ws layout:
//   WhhS  @ 0          819,200 B   [80 tile(ct*4+gb)][10 ks][64 L][8] bf16
//   WihS  @ 819,200  1,556,480 B   (fallback only)
//   biasq @ 2,375,680    5,120 B   [320*4] f32 quad-interleaved
//   Wq    @ 2,380,800 1,536,000 B  (full only)
//   G     @ 3,916,800 240,000,000B [2][50000][1200] bf16, col' = j*4+gate
// FULL total = 243,916,800 B; smaller ws -> on-the-fly fallback kernel.

typedef __attribute__((ext_vector_type(8))) short s16x8;
typedef __attribute__((ext_vector_type(4))) short s16x4;
typedef __attribute__((ext_vector_type(4))) float f32x4;

#define FULL_WS_BYTES 243916800ull

__device__ __forceinline__ float bf2f(short s) {
  unsigned u = ((unsigned)(unsigned short)s) << 16;
  float f; __builtin_memcpy(&f, &u, 4); return f;
}
__device__ __forceinline__ short f2bf(float f) {
  unsigned u; __builtin_memcpy(&u, &f, 4);
  unsigned r = u + 0x7fffu + ((u >> 16) & 1u);   // RNE
  return (short)(r >> 16);
}
__device__ __forceinline__ f32x4 mfma16(s16x8 a, s16x8 b, f32x4 c) {
  return __builtin_amdgcn_mfma_f32_16x16x32_bf16(a, b, c, 0, 0, 0);
}
__device__ __forceinline__ float sigm(float x) { return 1.f / (1.f + __expf(-x)); }
__device__ __forceinline__ float tanh_(float x) {
  float e = __expf(2.f * x);          // inf-safe
  return 1.f - 2.f / (e + 1.f);
}

// ---------------- prep: weight fragment swizzles + bias ----------------
__global__ void prep_w(const float* __restrict__ Wih, const float* __restrict__ Whh_in,
                       const float* __restrict__ bih, const float* __restrict__ bhh,
                       short* __restrict__ Wq, short* __restrict__ WhhS,
                       short* __restrict__ WihS, float* __restrict__ biasq, int full) {
  int idx = blockIdx.x * 256 + threadIdx.x;       // 960*256 = 245,760
  if (idx < 96000) {                              // Wq (full path only)
    if (!full) return;
    int tab = idx / 48000; int r = idx % 48000;
    int L = r % 64;
    int colp = (r / 640) * 16 + (L & 15);
    int rowW = (colp & 3) * 300 + (colp >> 2);    // gate*300 + j
#pragma unroll
    for (int i = 0; i < 8; ++i) {
      int k = ((r / 64) % 10) * 32 + (L >> 4) * 8 + i;
      float v = (k < 300) ? Wih[(size_t)rowW * 600 + 300 * tab + k] : 0.f;
      Wq[(size_t)idx * 8 + i] = f2bf(v);
    }
  } else if (idx < 147200) {                      // WhhS
    int r = idx - 96000;
    int tIdx = r / 640; int L = r % 64;
    int ct = tIdx >> 2, gb = tIdx & 3;
    int j = ct * 16 + (L & 15);
#pragma unroll
    for (int i = 0; i < 8; ++i) {
      int k = ((r / 64) % 10) * 32 + (L >> 4) * 8 + i;
      float v = (j < 300 && k < 300) ? Whh_in[(size_t)(gb * 300 + j) * 300 + k] : 0.f;
      WhhS[(size_t)r * 8 + i] = f2bf(v);
    }
  } else if (idx < 244480) {                      // WihS (fallback)
    int r = idx - 147200;
    int tile = r / 1216; int L = r % 64;
    int ct = tile >> 2, gb = tile & 3;
    int j = ct * 16 + (L & 15);
    int ksg = (r / 64) % 19;
#pragma unroll
    for (int i = 0; i < 8; ++i) {
      int k = ksg * 32 + (L >> 4) * 8 + i;
      float v = (j < 300 && k < 600) ? Wih[(size_t)(gb * 300 + j) * 600 + k] : 0.f;
      WihS[(size_t)r * 8 + i] = f2bf(v);
    }
  } else if (idx < 245760) {                      // biasq
    int r = idx - 244480; int j = r >> 2, gb = r & 3;
    biasq[r] = (j < 300) ? (bih[gb * 300 + j] + bhh[gb * 300 + j]) : 0.f;
  }
}

// ---------------- table GEMM: G[tab][v][col'] = glove @ W^T ----------------
__device__ __forceinline__ s16x8 loadA_gl(const float* __restrict__ g, int r, int k0) {
  s16x8 v;
  if (r < 50000) {
    if (k0 + 8 <= 300) {
      const float* p = g + (size_t)r * 300 + k0;
      f32x4 a = *(const f32x4*)p, b = *(const f32x4*)(p + 4);
      v[0] = f2bf(a.x); v[1] = f2bf(a.y); v[2] = f2bf(a.z); v[3] = f2bf(a.w);
      v[4] = f2bf(b.x); v[5] = f2bf(b.y); v[6] = f2bf(b.z); v[7] = f2bf(b.w);
    } else {
#pragma unroll
      for (int i = 0; i < 8; ++i) {
        int k = k0 + i;
        v[i] = (k < 300) ? f2bf(g[(size_t)r * 300 + k]) : (short)0;
      }
    }
  } else {
#pragma unroll
    for (int i = 0; i < 8; ++i) v[i] = 0;
  }
  return v;
}

__global__ __launch_bounds__(256, 2) void tab_gemm(const float* __restrict__ gl,
                                                   const short* __restrict__ Wq,
                                                   short* __restrict__ G) {
  int bid = blockIdx.x;                 // 391*15 blocks
  int nt = bid % 15, mt = bid / 15;
  int tid = threadIdx.x, L = tid & 63, w = tid >> 6;
  int ln = L & 15, kg = L >> 4;
  int v0 = mt * 128;

  f32x4 acc[2][2][5];
#pragma unroll
  for (int a = 0; a < 2; ++a)
#pragma unroll
    for (int b = 0; b < 2; ++b)
#pragma unroll
      for (int c = 0; c < 5; ++c) acc[a][b][c] = (f32x4){0.f, 0.f, 0.f, 0.f};

#pragma unroll
  for (int ks = 0; ks < 10; ++ks) {
    int r0 = v0 + (2 * w) * 16 + ln;
    int k0 = ks * 32 + kg * 8;
    s16x8 A0 = loadA_gl(gl, r0, k0);
    s16x8 A1 = loadA_gl(gl, r0 + 16, k0);
#pragma unroll
    for (int tab = 0; tab < 2; ++tab)
#pragma unroll
      for (int ctl = 0; ctl < 5; ++ctl) {
        const short* bp = Wq + ((((size_t)tab * 75 + nt * 5 + ctl) * 10 + ks) * 64 + L) * 8;
        s16x8 B = *(const s16x8*)bp;
        acc[tab][0][ctl] = mfma16(A0, B, acc[tab][0][ctl]);
        acc[tab][1][ctl] = mfma16(A1, B, acc[tab][1][ctl]);
      }
  }
#pragma unroll
  for (int tab = 0; tab < 2; ++tab)
#pragma unroll
    for (int rtl = 0; rtl < 2; ++rtl)
#pragma unroll
      for (int ctl = 0; ctl < 5; ++ctl)
#pragma unroll
        for (int r = 0; r < 4; ++r) {
          int v = v0 + (2 * w + rtl) * 16 + kg * 4 + r;
          if (v < 50000) {
            int colp = nt * 80 + ctl * 16 + ln;
            G[((size_t)tab * 50000 + v) * 1200 + colp] = f2bf(acc[tab][rtl][ctl][r]);
          }
        }
}

// ------- recurrent kernel, W_hh register-persistent: 16 WGs x 640 thr (10 waves) -------
struct TailSh10 { float pool[16][304]; float l1[16][100]; float l2[16][5]; };
struct LoopSh10 { short h[2][16][330]; };         // 21,120 B (stride 330: bank-stride 5)
union Sh10 { LoopSh10 loop; TailSh10 tail; };     // 26,176 B

__global__ __launch_bounds__(640, 1) void lstm_reg(
    const int* __restrict__ ids, const short* __restrict__ G,
    const short* __restrict__ Whh, const float* __restrict__ biasq,
    const float* __restrict__ W1, const float* __restrict__ b1,
    const float* __restrict__ W2, const float* __restrict__ b2,
    float* __restrict__ out) {
  __shared__ Sh10 sh;

  const int tid = threadIdx.x;
  const int L = tid & 63, w = tid >> 6;           // 10 waves
  const int ln = L & 15, kg = L >> 4;
  const int b0 = blockIdx.x * 16;
  const int ct0 = w, ct1 = w + 10;                // 20 col-tiles, 2 per wave

  const int j0 = ct0 * 16 + ln, j1 = ct1 * 16 + ln;
  const int jc0 = (j0 < 300) ? j0 : 299, jc1 = (j1 < 300) ? j1 : 299;
  const bool ok0 = (j0 < 300), ok1 = (j1 < 300);
  const f32x4 bq0 = *(const f32x4*)(biasq + 4 * j0);
  const f32x4 bq1 = *(const f32x4*)(biasq + 4 * j1);

  // ---- load W_hh B-fragments into persistent registers (once) ----
  s16x8 B0[4][10], B1[4][10];
#pragma unroll
  for (int gb = 0; gb < 4; ++gb)
#pragma unroll
    for (int ks = 0; ks < 10; ++ks) {
      B0[gb][ks] = *(const s16x8*)(Whh + (size_t)(ct0 * 4 + gb) * 5120 + (ks * 64 + L) * 8);
      B1[gb][ks] = *(const s16x8*)(Whh + (size_t)(ct1 * 4 + gb) * 5120 + (ks * 64 + L) * 8);
    }
  // Opaque redefinition: the values' defs become this asm, so the compiler
  // CANNOT re-materialize the loads inside the t-loop (R9: it did, VGPR=84).
  // Forces all 80 fragments (320 VGPRs) to stay allocated across the loop.
#pragma unroll
  for (int gb = 0; gb < 4; ++gb)
#pragma unroll
    for (int ks = 0; ks < 10; ++ks) {
      asm volatile("" : "+v"(B0[gb][ks]));
      asm volatile("" : "+v"(B1[gb][ks]));
    }

  float creg[2][4] = {}, pool[2][4] = {};
  int id_cur[4], id_prev[4];
#pragma unroll
  for (int r = 0; r < 4; ++r) {
    id_cur[r] = ids[(size_t)(b0 + kg * 4 + r) * 512 + 0];
    id_prev[r] = id_cur[r];                       // unused at t=0 (g2=0)
  }

  for (int i = tid; i < (int)(sizeof(LoopSh10) / 2); i += 640) ((short*)&sh.loop)[i] = 0;
  __syncthreads();

  const s16x4 zq = (s16x4){0, 0, 0, 0};

  for (int t = 0; t < 512; ++t) {
    // phase 1: issue ALL VM loads first; latency hides under the MFMA phase
    // (MFMA depends only on LDS-A + register-B, never waits on these).
    s16x4 gq1[2][4], gq2[2][4];
#pragma unroll
    for (int r = 0; r < 4; ++r) {
      gq1[0][r] = (t != 511) ? *(const s16x4*)(G + (size_t)id_cur[r] * 1200 + 4 * jc0) : zq;
      gq1[1][r] = (t != 511) ? *(const s16x4*)(G + (size_t)id_cur[r] * 1200 + 4 * jc1) : zq;
      gq2[0][r] = (t != 0) ? *(const s16x4*)(G + ((size_t)50000 + id_prev[r]) * 1200 + 4 * jc0) : zq;
      gq2[1][r] = (t != 0) ? *(const s16x4*)(G + ((size_t)50000 + id_prev[r]) * 1200 + 4 * jc1) : zq;
    }
    int idn[4];
    {
      int tn = (t < 511) ? t + 1 : 511;
#pragma unroll
      for (int r = 0; r < 4; ++r)
        idn[r] = ids[(size_t)(b0 + kg * 4 + r) * 512 + tn];
    }

    // phase 2: A fragments from LDS h dbuf (read (t+1)&1)
    s16x8 A[10];
#pragma unroll
    for (int ks = 0; ks < 10; ++ks)
      A[ks] = *(const s16x8*)(&sh.loop.h[(t + 1) & 1][ln][ks * 32 + kg * 8]);

    // phase 3: 80 MFMA, all operands in registers
    f32x4 acc[2][4];
#pragma unroll
    for (int gb = 0; gb < 4; ++gb) {
      f32x4 a0 = (f32x4){0.f, 0.f, 0.f, 0.f};
      f32x4 a1 = (f32x4){0.f, 0.f, 0.f, 0.f};
#pragma unroll
      for (int ks = 0; ks < 10; ++ks) {
        a0 = mfma16(A[ks], B0[gb][ks], a0);
        a1 = mfma16(A[ks], B1[gb][ks], a1);
      }
      acc[0][gb] = a0; acc[1][gb] = a1;
    }

    // phase 4: epilogue (gathers have landed under the MFMA shadow)
#pragma unroll
    for (int s = 0; s < 2; ++s) {
      const int j = s ? j1 : j0;
      const bool ok = s ? ok1 : ok0;
      const f32x4 bq = s ? bq1 : bq0;
#pragma unroll
      for (int r = 0; r < 4; ++r) {
        s16x4 q1 = gq1[s][r], q2 = gq2[s][r];
        float pi = acc[s][0][r] + bf2f(q1.x) + bf2f(q2.x) + bq.x;
        float pf = acc[s][1][r] + bf2f(q1.y) + bf2f(q2.y) + bq.y;
        float pg = acc[s][2][r] + bf2f(q1.z) + bf2f(q2.z) + bq.z;
        float po = acc[s][3][r] + bf2f(q1.w) + bf2f(q2.w) + bq.w;
        float iv = sigm(pi), fv = sigm(pf), gv = tanh_(pg), ov = sigm(po);
        float c = fv * creg[s][r] + iv * gv;
        creg[s][r] = c;
        float h = ov * tanh_(c);
        if (ok) {                                 // pad cols stay zero in LDS
          pool[s][r] += h;
          sh.loop.h[t & 1][kg * 4 + r][j] = f2bf(h);
        }
      }
    }

#pragma unroll
    for (int r = 0; r < 4; ++r) { id_prev[r] = id_cur[r]; id_cur[r] = idn[r]; }
    __syncthreads();                              // vmcnt near-empty -> cheap
  }

  // ---- tail: pooled mean -> l1 -> l2 -> log_softmax ----
#pragma unroll
  for (int s = 0; s < 2; ++s) {
    const int j = s ? j1 : j0;
    if (j < 300) {
#pragma unroll
      for (int r = 0; r < 4; ++r)
        sh.tail.pool[kg * 4 + r][j] = pool[s][r] * (1.f / 512.f);
    }
  }
  __syncthreads();

  for (int k = 0; k < 3; ++k) {                   // 1600 dots of 300
    int it = tid + 640 * k;
    if (it < 1600) {
      int b = it & 15, o = it >> 4;
      const float* w1r = W1 + (size_t)o * 300;
      float d = b1[o];
      for (int q = 0; q < 75; ++q) {
        f32x4 pv = *(const f32x4*)(&sh.tail.pool[b][q * 4]);
        f32x4 wv = *(const f32x4*)(w1r + q * 4);
        d += pv.x * wv.x + pv.y * wv.y + pv.z * wv.z + pv.w * wv.w;
      }
      sh.tail.l1[b][o] = sigm(d);
    }
  }
  __syncthreads();
  if (tid < 80) {
    int b = tid & 15, o = tid >> 4;
    float d = b2[o];
    for (int q = 0; q < 100; ++q) d += sh.tail.l1[b][q] * W2[o * 100 + q];
    sh.tail.l2[b][o] = sigm(d);
  }
  __syncthreads();
  if (tid < 16) {
    float x0 = sh.tail.l2[tid][0], x1 = sh.tail.l2[tid][1], x2 = sh.tail.l2[tid][2],
          x3 = sh.tail.l2[tid][3], x4 = sh.tail.l2[tid][4];
    float m = fmaxf(fmaxf(fmaxf(x0, x1), fmaxf(x2, x3)), x4);
    float ssum = __expf(x0 - m) + __expf(x1 - m) + __expf(x2 - m) +
                 __expf(x3 - m) + __expf(x4 - m);
    float ls = __logf(ssum);
    float* po = out + (size_t)(b0 + tid) * 5;
    po[0] = x0 - m - ls; po[1] = x1 - m - ls; po[2] = x2 - m - ls;
    po[3] = x3 - m - ls; po[4] = x4 - m - ls;
  }
}

// ---------------- fallback (small ws): on-the-fly input GEMM, 16 WGs ----------------
struct TailShF { float pool[16][304]; float l1[16][100]; float l2[16][5]; };
struct LoopOF { short h[2][16][330]; short x[2][16][616]; };
union ShFb { LoopOF loop; TailShF tail; };

__global__ __launch_bounds__(512, 2) void lstm_fb(
    const int* __restrict__ ids, const float* __restrict__ glove,
    const short* __restrict__ Whh, const short* __restrict__ WihF,
    const float* __restrict__ biasq,
    const float* __restrict__ W1, const float* __restrict__ b1,
    const float* __restrict__ W2, const float* __restrict__ b2,
    float* __restrict__ out) {
  __shared__ ShFb sh;

  const int tid = threadIdx.x;
  const int L = tid & 63, w = tid >> 6;
  const int ln = L & 15, kg = L >> 4;
  const int b0 = blockIdx.x * 16;
  const int nct = (w < 4) ? 3 : 2;
  const int cts[3] = {w, w + 8, w + 16};

  int jj[3];
  f32x4 bq[3];
#pragma unroll
  for (int s = 0; s < 3; ++s) {
    jj[s] = cts[s] * 16 + ln;
    if (s < nct) bq[s] = *(const f32x4*)(biasq + 4 * jj[s]);
  }
  float creg[3][4] = {}, pool[3][4] = {};

  for (int i = tid; i < (int)(sizeof(sh.loop) / 2); i += 512) ((short*)&sh.loop)[i] = 0;
  __syncthreads();

  for (int t = 0; t < 512; ++t) {
    {
      int r2 = tid >> 5, cl = tid & 31;
      int idt = (t < 511) ? ids[(size_t)(b0 + r2) * 512 + t] : 0;
#pragma unroll
      for (int q = 0; q < 10; ++q) {
        int c = cl + 32 * q;
        if (c < 300) {
          float v = (t < 511) ? glove[(size_t)idt * 300 + c] : 0.f;
          short bv = f2bf(v);
          sh.loop.x[t & 1][r2][c] = bv;
          sh.loop.x[(t + 1) & 1][r2][300 + c] = bv;
        }
      }
      __syncthreads();
    }

    s16x8 A[10];
#pragma unroll
    for (int ks = 0; ks < 10; ++ks)
      A[ks] = *(const s16x8*)(&sh.loop.h[(t + 1) & 1][ln][ks * 32 + kg * 8]);
    s16x8 AX[19];
#pragma unroll
    for (int ks = 0; ks < 19; ++ks)
      AX[ks] = *(const s16x8*)(&sh.loop.x[t & 1][ln][ks * 32 + kg * 8]);

    f32x4 acc[3][4];
#pragma unroll
    for (int s = 0; s < 3; ++s) {
      if (s >= nct) continue;
#pragma unroll
      for (int gb = 0; gb < 4; ++gb) {
        f32x4 a = (f32x4){0.f, 0.f, 0.f, 0.f};
        const short* wb = Whh + (size_t)(cts[s] * 4 + gb) * 5120;
#pragma unroll
        for (int ks = 0; ks < 10; ++ks)
          a = mfma16(A[ks], *(const s16x8*)(wb + (ks * 64 + L) * 8), a);
        const short* wx = WihF + (size_t)(cts[s] * 4 + gb) * 19 * 512;
#pragma unroll
        for (int ks = 0; ks < 19; ++ks)
          a = mfma16(AX[ks], *(const s16x8*)(wx + (ks * 64 + L) * 8), a);
        acc[s][gb] = a;
      }
    }

#pragma unroll
    for (int s = 0; s < 3; ++s) {
      if (s >= nct) continue;
      const int j = jj[s];
#pragma unroll
      for (int r = 0; r < 4; ++r) {
        float pi = acc[s][0][r] + bq[s].x;
        float pf = acc[s][1][r] + bq[s].y;
        float pg = acc[s][2][r] + bq[s].z;
        float po = acc[s][3][r] + bq[s].w;
        float iv = sigm(pi), fv = sigm(pf), gv = tanh_(pg), ov = sigm(po);
        float c = fv * creg[s][r] + iv * gv;
        creg[s][r] = c;
        float h = ov * tanh_(c);
        if (j >= 300) h = 0.f;
        pool[s][r] += h;
        sh.loop.h[t & 1][kg * 4 + r][j] = f2bf(h);
      }
    }
    __syncthreads();
  }

#pragma unroll
  for (int s = 0; s < 3; ++s) {
    if (s >= nct) continue;
    if (jj[s] < 300) {
#pragma unroll
      for (int r = 0; r < 4; ++r)
        sh.tail.pool[kg * 4 + r][jj[s]] = pool[s][r] * (1.f / 512.f);
    }
  }
  __syncthreads();
  for (int k = 0; k < 4; ++k) {
    int it = tid + 512 * k;
    if (it < 1600) {
      int b = it & 15, o = it >> 4;
      const float* w1r = W1 + (size_t)o * 300;
      float d = b1[o];
      for (int q = 0; q < 75; ++q) {
        f32x4 pv = *(const f32x4*)(&sh.tail.pool[b][q * 4]);
        f32x4 wv = *(const f32x4*)(w1r + q * 4);
        d += pv.x * wv.x + pv.y * wv.y + pv.z * wv.z + pv.w * wv.w;
      }
      sh.tail.l1[b][o] = sigm(d);
    }
  }
  __syncthreads();
  if (tid < 80) {
    int b = tid & 15, o = tid >> 4;
    float d = b2[o];
    for (int q = 0; q < 100; ++q) d += sh.tail.l1[b][q] * W2[o * 100 + q];
    sh.tail.l2[b][o] = sigm(d);
  }
  __syncthreads();
  if (tid < 16) {
    float x0 = sh.tail.l2[tid][0], x1 = sh.tail.l2[tid][1], x2 = sh.tail.l2[tid][2],
          x3 = sh.tail.l2[tid][3], x4 = sh.tail.l2[tid][4];
    float m = fmaxf(fmaxf(fmaxf(x0, x1), fmaxf(x2, x3)), x4);
    float ssum = __expf(x0 - m) + __expf(x1 - m) + __expf(x2 - m) +
                 __expf(x3 - m) + __expf(x4 - m);
    float ls = __logf(ssum);
    float* po = out + (size_t)(b0 + tid) * 5;
    po[0] = x0 - m - ls; po[1] = x1 - m - ls; po[2] = x2 - m - ls;
    po[3] = x3 - m - ls; po[4] = x4 - m - ls;
  }
}

extern "C" void kernel_launch(void* const* d_in, const int* in_sizes, int n_in,
                              void* d_out, int out_size, void* d_ws, size_t ws_size,
                              hipStream_t stream) {
  const int*   ids   = (const int*)d_in[0];
  const float* glove = (const float*)d_in[2];
  const float* W_ih  = (const float*)d_in[3];
  const float* W_hh  = (const float*)d_in[4];
  const float* b_ih  = (const float*)d_in[5];
  const float* b_hh  = (const float*)d_in[6];
  const float* W1    = (const float*)d_in[7];
  const float* b1    = (const float*)d_in[8];
  const float* W2    = (const float*)d_in[9];
  const float* b2    = (const float*)d_in[10];
  float* out = (float*)d_out;

  char* ws = (char*)d_ws;
  short* WhhS  = (short*)(ws);                   //   819,200 B
  short* WihS  = (short*)(ws + 819200);          // 1,556,480 B (fallback only)
  float* biasq = (float*)(ws + 2375680);         //     5,120 B
  short* Wq    = (short*)(ws + 2380800);         // 1,536,000 B (full only)
  short* G     = (short*)(ws + 3916800);         // 240,000,000 B (full only)

  const int full = (ws_size >= (size_t)FULL_WS_BYTES) ? 1 : 0;

  prep_w<<<960, 256, 0, stream>>>(W_ih, W_hh, b_ih, b_hh, Wq, WhhS, WihS, biasq, full);
  if (full) {
    tab_gemm<<<5865, 256, 0, stream>>>(glove, Wq, G);
    lstm_reg<<<16, 640, 0, stream>>>(ids, G, WhhS, biasq, W1, b1, W2, b2, out);
  } else {
    lstm_fb<<<16, 512, 0, stream>>>(ids, glove, WhhS, WihS, biasq,
                                    W1, b1, W2, b2, out);
  }
}